// Round 1
// baseline (352.773 us; speedup 1.0000x reference)
//
#include <hip/hip_runtime.h>
#include <hip/hip_bf16.h>

#define NN 1024
#define NE 32768
#define TAU 0.7f

// ---------------- small precompute: C2s[2,768], Wm1s[3,768], Wm2s[3,256] ----------------
__global__ void precompute_tabs(const float* __restrict__ class2, const float* __restrict__ wm1,
                                const float* __restrict__ wm2, float* __restrict__ C2s,
                                float* __restrict__ Wm1s, float* __restrict__ Wm2s) {
    int i = blockIdx.x * 256 + threadIdx.x;
    if (i < 1536) {                       // C2s: sum class2[j,k,:] over 64
        const float* p = class2 + (size_t)i * 64;
        float s = 0.f;
        for (int l = 0; l < 64; l++) s += p[l];
        C2s[i] = s;
    } else if (i < 1536 + 2304) {         // Wm1s: sum wm1[j,k,:] over 256
        int j = i - 1536;
        const float* p = wm1 + (size_t)j * 256;
        float s = 0.f;
        for (int l = 0; l < 256; l++) s += p[l];
        Wm1s[j] = s;
    } else if (i < 1536 + 2304 + 768) {   // Wm2s: sum wm2[j,k,:] over 256
        int j = i - 3840;
        const float* p = wm2 + (size_t)j * 256;
        float s = 0.f;
        for (int l = 0; l < 256; l++) s += p[l];
        Wm2s[j] = s;
    }
}

// ---------------- CSR build ----------------
__global__ void count_deg(const int* __restrict__ dst, int* __restrict__ deg) {
    int e = blockIdx.x * 256 + threadIdx.x;
    if (e < NE) atomicAdd(&deg[dst[e]], 1);
}

__global__ void scan_deg(const int* __restrict__ deg, int* __restrict__ rowst,
                         int* __restrict__ cursor, float* __restrict__ dinv) {
    __shared__ int s[NN];
    int i = threadIdx.x;
    int d = deg[i];
    s[i] = d;
    dinv[i] = d > 0 ? rsqrtf((float)d) : 0.0f;
    __syncthreads();
    for (int off = 1; off < NN; off <<= 1) {
        int t = (i >= off) ? s[i - off] : 0;
        __syncthreads();
        s[i] += t;
        __syncthreads();
    }
    rowst[i + 1] = s[i];
    if (i == 0) rowst[0] = 0;
    cursor[i] = (i == 0) ? 0 : s[i - 1];
}

__global__ void fill_adj(const int* __restrict__ src, const int* __restrict__ dst,
                         int* __restrict__ cursor, int* __restrict__ adj) {
    int e = blockIdx.x * 256 + threadIdx.x;
    if (e < NE) {
        int d = dst[e];
        int slot = atomicAdd(&cursor[d], 1);
        adj[slot] = src[e];
    }
}

// ---------------- fp32 tiled GEMM: C[M,N] = A[M,K] @ B[K,N] (+bias)(+relu) ----------------
template <int BM, int BN, int BK, int TM, int TN, bool BIAS, bool RELU>
__global__ __launch_bounds__((BM / TM) * (BN / TN)) void gemm_f32(
    const float* __restrict__ A, const float* __restrict__ B, const float* __restrict__ bias,
    float* __restrict__ C, int M, int N, int K) {
    static_assert(TN == 4, "epilogue assumes TN==4");
    constexpr int TX = BM / TM;
    constexpr int TY = BN / TN;
    constexpr int NT = TX * TY;
    __shared__ float As[BK][BM + 4];
    __shared__ float Bs[BK][BN];
    int tid = threadIdx.x;
    int tx = tid % TX;
    int ty = tid / TX;
    int m0 = blockIdx.x * BM;
    int n0 = blockIdx.y * BN;
    float acc[TM][TN];
#pragma unroll
    for (int i = 0; i < TM; i++)
#pragma unroll
        for (int j = 0; j < TN; j++) acc[i][j] = 0.f;

    for (int kt = 0; kt < K; kt += BK) {
        // A tile (transposed into LDS), float4 along K
#pragma unroll
        for (int v = tid; v < BM * BK / 4; v += NT) {
            int ar = v / (BK / 4);
            int ak = (v % (BK / 4)) * 4;
            float4 av = *(const float4*)(A + (size_t)(m0 + ar) * K + kt + ak);
            As[ak + 0][ar] = av.x;
            As[ak + 1][ar] = av.y;
            As[ak + 2][ar] = av.z;
            As[ak + 3][ar] = av.w;
        }
        // B tile, float4 along N
#pragma unroll
        for (int v = tid; v < BK * BN / 4; v += NT) {
            int bk = v / (BN / 4);
            int bn = (v % (BN / 4)) * 4;
            *(float4*)&Bs[bk][bn] = *(const float4*)(B + (size_t)(kt + bk) * N + n0 + bn);
        }
        __syncthreads();
#pragma unroll
        for (int k = 0; k < BK; k++) {
            float a[TM], b[TN];
#pragma unroll
            for (int i = 0; i < TM; i++) a[i] = As[k][tx * TM + i];
#pragma unroll
            for (int j = 0; j < TN; j++) b[j] = Bs[k][ty * TN + j];
#pragma unroll
            for (int i = 0; i < TM; i++)
#pragma unroll
                for (int j = 0; j < TN; j++) acc[i][j] += a[i] * b[j];
        }
        __syncthreads();
    }
    float4 bv = make_float4(0.f, 0.f, 0.f, 0.f);
    if (BIAS) bv = *(const float4*)(bias + n0 + ty * TN);
#pragma unroll
    for (int i = 0; i < TM; i++) {
        int m = m0 + tx * TM + i;
        float4 o;
        o.x = acc[i][0] + bv.x;
        o.y = acc[i][1] + bv.y;
        o.z = acc[i][2] + bv.z;
        o.w = acc[i][3] + bv.w;
        if (RELU) {
            o.x = fmaxf(o.x, 0.f); o.y = fmaxf(o.y, 0.f);
            o.z = fmaxf(o.z, 0.f); o.w = fmaxf(o.w, 0.f);
        }
        *(float4*)(C + (size_t)m * N + n0 + ty * TN) = o;
    }
}

// ---------------- heads: logits -> r (argmax routing), and g ----------------
__global__ void heads3(const float* __restrict__ h, const float* __restrict__ W3,
                       const float* __restrict__ b3, float* __restrict__ r) {
    int n = blockIdx.x;
    int lane = threadIdx.x;
    const float* hr = h + (size_t)n * 512;
    float p0 = 0.f, p1 = 0.f, p2 = 0.f;
    for (int k = lane; k < 512; k += 64) {
        float hv = hr[k];
        p0 += hv * W3[k * 3 + 0];
        p1 += hv * W3[k * 3 + 1];
        p2 += hv * W3[k * 3 + 2];
    }
    for (int off = 32; off; off >>= 1) {
        p0 += __shfl_down(p0, off);
        p1 += __shfl_down(p1, off);
        p2 += __shfl_down(p2, off);
    }
    if (lane == 0) {
        float l0 = p0 + b3[0], l1 = p1 + b3[1], l2 = p2 + b3[2];
        int am = 0;
        float mv = l0;
        if (l1 > mv) { mv = l1; am = 1; }
        if (l2 > mv) { mv = l2; am = 2; }
        float lo = (1.0f - TAU) * 0.5f;
        r[n * 4 + 0] = (am == 0) ? TAU : lo;
        r[n * 4 + 1] = (am == 1) ? TAU : lo;
        r[n * 4 + 2] = (am == 2) ? TAU : lo;
    }
}

__global__ void heads2(const float* __restrict__ h, const float* __restrict__ W3,
                       const float* __restrict__ b3, float* __restrict__ g) {
    int n = blockIdx.x;
    int lane = threadIdx.x;
    const float* hr = h + (size_t)n * 512;
    float p0 = 0.f, p1 = 0.f;
    for (int k = lane; k < 512; k += 64) {
        float hv = hr[k];
        p0 += hv * W3[k * 2 + 0];
        p1 += hv * W3[k * 2 + 1];
    }
    for (int off = 32; off; off >>= 1) {
        p0 += __shfl_down(p0, off);
        p1 += __shfl_down(p1, off);
    }
    if (lane == 0) {
        g[n * 2 + 0] = p0 + b3[0];
        g[n * 2 + 1] = p1 + b3[1];
    }
}

// ---------------- res1 = (x2*(g@C2s) + g@bp1) * (r@Wm1s) + r@bp2 ----------------
__global__ void res1_kernel(const float* __restrict__ x2, const float* __restrict__ g,
                            const float* __restrict__ r, const float* __restrict__ C2s,
                            const float* __restrict__ bp1, const float* __restrict__ Wm1s,
                            const float* __restrict__ bp2, float* __restrict__ res1) {
    int idx = blockIdx.x * blockDim.x + threadIdx.x;  // 1024*768/4
    int n = idx / 192;
    int kq = (idx % 192) * 4;
    float g0 = g[n * 2 + 0], g1 = g[n * 2 + 1];
    float r0 = r[n * 4 + 0], r1 = r[n * 4 + 1], r2 = r[n * 4 + 2];
    float4 xv = *(const float4*)(x2 + (size_t)n * 768 + kq);
    float4 c0 = *(const float4*)(C2s + kq);
    float4 c1 = *(const float4*)(C2s + 768 + kq);
    float4 p0 = *(const float4*)(bp1 + kq);
    float4 p1 = *(const float4*)(bp1 + 768 + kq);
    float4 w0 = *(const float4*)(Wm1s + kq);
    float4 w1 = *(const float4*)(Wm1s + 768 + kq);
    float4 w2 = *(const float4*)(Wm1s + 1536 + kq);
    float4 q0 = *(const float4*)(bp2 + kq);
    float4 q1 = *(const float4*)(bp2 + 768 + kq);
    float4 q2 = *(const float4*)(bp2 + 1536 + kq);
    float4 o;
    o.x = (xv.x * (g0 * c0.x + g1 * c1.x) + g0 * p0.x + g1 * p1.x) * (r0 * w0.x + r1 * w1.x + r2 * w2.x) + r0 * q0.x + r1 * q1.x + r2 * q2.x;
    o.y = (xv.y * (g0 * c0.y + g1 * c1.y) + g0 * p0.y + g1 * p1.y) * (r0 * w0.y + r1 * w1.y + r2 * w2.y) + r0 * q0.y + r1 * q1.y + r2 * q2.y;
    o.z = (xv.z * (g0 * c0.z + g1 * c1.z) + g0 * p0.z + g1 * p1.z) * (r0 * w0.z + r1 * w1.z + r2 * w2.z) + r0 * q0.z + r1 * q1.z + r2 * q2.z;
    o.w = (xv.w * (g0 * c0.w + g1 * c1.w) + g0 * p0.w + g1 * p1.w) * (r0 * w0.w + r1 * w1.w + r2 * w2.w) + r0 * q0.w + r1 * q1.w + r2 * q2.w;
    *(float4*)(res1 + (size_t)n * 768 + kq) = o;
}

// ---------------- GCN gather: out[n,k] = dinv[n]*sum_{s in adj(n)} dinv[s]*h[s,k] + b[k] ----------------
template <int D, int NPB, bool RELU>
__global__ void gcn_gather(const float* __restrict__ h, const int* __restrict__ rowst,
                           const int* __restrict__ adj, const float* __restrict__ dinv,
                           const float* __restrict__ bias, float* __restrict__ out) {
    int n = blockIdx.x * NPB + threadIdx.x / D;
    int k = threadIdx.x % D;
    int r0 = rowst[n], r1 = rowst[n + 1];
    float acc = 0.f;
    for (int i = r0; i < r1; i++) {
        int s = adj[i];
        acc += h[(size_t)s * D + k] * dinv[s];
    }
    float v = dinv[n] * acc + bias[k];
    if (RELU) v = fmaxf(v, 0.f);
    out[(size_t)n * D + k] = v;
}

// ---------------- res2 = (r@Wm2s) * ( (r@wm12)*relu(gcn1out) + 2e-4*(res1@wm13) ) ----------------
__global__ void combine_res2(const float* __restrict__ g1out, const float* __restrict__ wm13o,
                             const float* __restrict__ r, const float* __restrict__ wm12,
                             const float* __restrict__ Wm2s, float* __restrict__ res2) {
    int idx = blockIdx.x * blockDim.x + threadIdx.x;  // 1024*256/4
    int n = idx / 64;
    int kq = (idx % 64) * 4;
    float r0 = r[n * 4 + 0], r1 = r[n * 4 + 1], r2 = r[n * 4 + 2];
    float4 a0 = *(const float4*)(wm12 + kq);
    float4 a1 = *(const float4*)(wm12 + 256 + kq);
    float4 a2 = *(const float4*)(wm12 + 512 + kq);
    float4 w0 = *(const float4*)(Wm2s + kq);
    float4 w1 = *(const float4*)(Wm2s + 256 + kq);
    float4 w2 = *(const float4*)(Wm2s + 512 + kq);
    float4 gv = *(const float4*)(g1out + (size_t)n * 256 + kq);
    float4 mv = *(const float4*)(wm13o + (size_t)n * 256 + kq);
    float4 o;
    o.x = (r0 * w0.x + r1 * w1.x + r2 * w2.x) * ((r0 * a0.x + r1 * a1.x + r2 * a2.x) * fmaxf(gv.x, 0.f) + 2e-4f * mv.x);
    o.y = (r0 * w0.y + r1 * w1.y + r2 * w2.y) * ((r0 * a0.y + r1 * a1.y + r2 * a2.y) * fmaxf(gv.y, 0.f) + 2e-4f * mv.y);
    o.z = (r0 * w0.z + r1 * w1.z + r2 * w2.z) * ((r0 * a0.z + r1 * a1.z + r2 * a2.z) * fmaxf(gv.z, 0.f) + 2e-4f * mv.z);
    o.w = (r0 * w0.w + r1 * w1.w + r2 * w2.w) * ((r0 * a0.w + r1 * a1.w + r2 * a2.w) * fmaxf(gv.w, 0.f) + 2e-4f * mv.w);
    *(float4*)(res2 + (size_t)n * 256 + kq) = o;
}

// ---------------- final: log_softmax(h2 @ fc_W + fc_b) ----------------
__global__ void final_fc(const float* __restrict__ h2, const float* __restrict__ fcW,
                         const float* __restrict__ fcb, float* __restrict__ out) {
    int t = threadIdx.x;             // 256 = 32 nodes x 8 outputs
    int n = blockIdx.x * 32 + t / 8;
    int j = t % 8;
    const float* hr = h2 + (size_t)n * 32;
    float acc = fcb[j];
#pragma unroll
    for (int i = 0; i < 32; i++) acc += hr[i] * fcW[i * 8 + j];
    float m = acc;
    for (int off = 4; off; off >>= 1) m = fmaxf(m, __shfl_xor(m, off, 8));
    float e = expf(acc - m);
    float s = e;
    for (int off = 4; off; off >>= 1) s += __shfl_xor(s, off, 8);
    out[(size_t)n * 8 + j] = acc - m - logf(s);
}

extern "C" void kernel_launch(void* const* d_in, const int* in_sizes, int n_in,
                              void* d_out, int out_size, void* d_ws, size_t ws_size,
                              hipStream_t stream) {
    const float* x1     = (const float*)d_in[0];
    const float* x11    = (const float*)d_in[1];
    const float* x2     = (const float*)d_in[2];
    const float* mlp_W1 = (const float*)d_in[3];
    const float* mlp_b1 = (const float*)d_in[4];
    const float* mlp_W2 = (const float*)d_in[5];
    const float* mlp_b2 = (const float*)d_in[6];
    const float* mlp_W3 = (const float*)d_in[7];
    const float* mlp_b3 = (const float*)d_in[8];
    const float* m1_W1  = (const float*)d_in[9];
    const float* m1_b1  = (const float*)d_in[10];
    const float* m1_W2  = (const float*)d_in[11];
    const float* m1_b2  = (const float*)d_in[12];
    const float* m1_W3  = (const float*)d_in[13];
    const float* m1_b3  = (const float*)d_in[14];
    const float* wm1    = (const float*)d_in[15];
    const float* bp1    = (const float*)d_in[16];
    const float* bp2    = (const float*)d_in[17];
    const float* wm12   = (const float*)d_in[18];
    const float* wm13   = (const float*)d_in[19];
    const float* class2 = (const float*)d_in[20];
    const float* gcn1_W = (const float*)d_in[21];
    const float* gcn1_b = (const float*)d_in[22];
    const float* wm2    = (const float*)d_in[23];
    const float* gcn2_W = (const float*)d_in[24];
    const float* gcn2_b = (const float*)d_in[25];
    const float* fc_W   = (const float*)d_in[26];
    const float* fc_b   = (const float*)d_in[27];
    const int* eidx     = (const int*)d_in[28];
    const int* esrc = eidx;
    const int* edst = eidx + NE;

    char* ws = (char*)d_ws;
    // region A [0,2MB): hs1 -> later {gcnh, wm13o}
    // region B [2MB,4MB): hs2 -> later {g1out, res2}
    // region C [4MB,7MB): res1 -> later {g2h, g2out}
    float* hs1   = (float*)(ws + 0);
    float* hs2   = (float*)(ws + (2u << 20));
    float* res1  = (float*)(ws + (4u << 20));
    float* gcnh  = (float*)(ws + 0);
    float* wm13o = (float*)(ws + (1u << 20));
    float* g1out = (float*)(ws + (2u << 20));
    float* res2  = (float*)(ws + (3u << 20));
    float* g2h   = (float*)(ws + (4u << 20));
    float* g2out = (float*)(ws + (4u << 20) + 131072);
    // tail at 7MB
    float* rbuf  = (float*)(ws + (7u << 20));       // [1024,4] (3 used)
    float* gbuf  = rbuf + 4096;                      // [1024,2]
    float* C2s   = gbuf + 2048;                      // [2,768]
    float* Wm1s  = C2s + 1536;                       // [3,768]
    float* Wm2s  = Wm1s + 2304;                      // [3,256]
    float* dinv  = Wm2s + 768;                       // [1024]
    int*   deg   = (int*)(dinv + 1024);              // [1024]
    int*   rowst = deg + 1024;                       // [1025]
    int*   cursor= rowst + 1040;                     // [1024]
    int*   adj   = cursor + 1024;                    // [32768]

    hipMemsetAsync(deg, 0, NN * sizeof(int), stream);
    precompute_tabs<<<18, 256, 0, stream>>>(class2, wm1, wm2, C2s, Wm1s, Wm2s);
    count_deg<<<NE / 256, 256, 0, stream>>>(edst, deg);
    scan_deg<<<1, NN, 0, stream>>>(deg, rowst, cursor, dinv);
    fill_adj<<<NE / 256, 256, 0, stream>>>(esrc, edst, cursor, adj);

    // x1 path (fp32 throughout: protects argmax routing)
    gemm_f32<64, 64, 16, 4, 4, true, true><<<dim3(16, 8), 256, 0, stream>>>(x1, mlp_W1, mlp_b1, hs1, 1024, 512, 768);
    gemm_f32<64, 64, 16, 4, 4, true, true><<<dim3(16, 8), 256, 0, stream>>>(hs1, mlp_W2, mlp_b2, hs2, 1024, 512, 512);
    heads3<<<NN, 64, 0, stream>>>(hs2, mlp_W3, mlp_b3, rbuf);

    // x11 path
    gemm_f32<64, 64, 16, 4, 4, true, true><<<dim3(16, 8), 256, 0, stream>>>(x11, m1_W1, m1_b1, hs1, 1024, 512, 768);
    gemm_f32<64, 64, 16, 4, 4, true, true><<<dim3(16, 8), 256, 0, stream>>>(hs1, m1_W2, m1_b2, hs2, 1024, 512, 512);
    heads2<<<NN, 64, 0, stream>>>(hs2, m1_W3, m1_b3, gbuf);

    res1_kernel<<<768, 256, 0, stream>>>(x2, gbuf, rbuf, C2s, bp1, Wm1s, bp2, res1);

    gemm_f32<64, 64, 16, 4, 4, false, false><<<dim3(16, 4), 256, 0, stream>>>(res1, gcn1_W, nullptr, gcnh, 1024, 256, 768);
    gemm_f32<64, 64, 16, 4, 4, false, false><<<dim3(16, 4), 256, 0, stream>>>(res1, wm13, nullptr, wm13o, 1024, 256, 768);
    gcn_gather<256, 1, false><<<NN, 256, 0, stream>>>(gcnh, rowst, adj, dinv, gcn1_b, g1out);
    combine_res2<<<256, 256, 0, stream>>>(g1out, wm13o, rbuf, wm12, Wm2s, res2);

    gemm_f32<64, 32, 16, 4, 4, false, false><<<dim3(16, 1), 128, 0, stream>>>(res2, gcn2_W, nullptr, g2h, 1024, 32, 256);
    gcn_gather<32, 2, true><<<NN / 2, 64, 0, stream>>>(g2h, rowst, adj, dinv, gcn2_b, g2out);

    final_fc<<<32, 256, 0, stream>>>(g2out, fc_W, fc_b, (float*)d_out);
}

// Round 2
// 261.428 us; speedup vs baseline: 1.3494x; 1.3494x over previous
//
#include <hip/hip_runtime.h>
#include <hip/hip_bf16.h>

#define NN 1024
#define NE 32768
#define TAU 0.7f

// ---------------- small precompute: C2s[2,768], Wm1s[3,768], Wm2s[3,256] ----------------
__global__ void precompute_tabs(const float* __restrict__ class2, const float* __restrict__ wm1,
                                const float* __restrict__ wm2, float* __restrict__ C2s,
                                float* __restrict__ Wm1s, float* __restrict__ Wm2s) {
    int i = blockIdx.x * 256 + threadIdx.x;
    if (i < 1536) {
        const float* p = class2 + (size_t)i * 64;
        float s = 0.f;
        for (int l = 0; l < 64; l++) s += p[l];
        C2s[i] = s;
    } else if (i < 1536 + 2304) {
        int j = i - 1536;
        const float* p = wm1 + (size_t)j * 256;
        float s = 0.f;
        for (int l = 0; l < 256; l++) s += p[l];
        Wm1s[j] = s;
    } else if (i < 1536 + 2304 + 768) {
        int j = i - 3840;
        const float* p = wm2 + (size_t)j * 256;
        float s = 0.f;
        for (int l = 0; l < 256; l++) s += p[l];
        Wm2s[j] = s;
    }
}

// ---------------- CSR build ----------------
__global__ void count_deg(const int* __restrict__ dst, int* __restrict__ deg) {
    int e = blockIdx.x * 256 + threadIdx.x;
    if (e < NE) atomicAdd(&deg[dst[e]], 1);
}

__global__ void scan_deg(const int* __restrict__ deg, int* __restrict__ rowst,
                         int* __restrict__ cursor, float* __restrict__ dinv) {
    __shared__ int s[NN];
    int i = threadIdx.x;
    int d = deg[i];
    s[i] = d;
    dinv[i] = d > 0 ? rsqrtf((float)d) : 0.0f;
    __syncthreads();
    for (int off = 1; off < NN; off <<= 1) {
        int t = (i >= off) ? s[i - off] : 0;
        __syncthreads();
        s[i] += t;
        __syncthreads();
    }
    rowst[i + 1] = s[i];
    if (i == 0) rowst[0] = 0;
    cursor[i] = (i == 0) ? 0 : s[i - 1];
}

__global__ void fill_adj(const int* __restrict__ src, const int* __restrict__ dst,
                         int* __restrict__ cursor, int* __restrict__ adj) {
    int e = blockIdx.x * 256 + threadIdx.x;
    if (e < NE) {
        int d = dst[e];
        int slot = atomicAdd(&cursor[d], 1);
        adj[slot] = src[e];
    }
}

// ---------------- fp32 split-K pair GEMM, atomic accumulate into zeroed C ----------------
// z = pair*KS + ks ; C += A[:, k0:k0+chunk] @ B[k0:k0+chunk, :]
// ARELU: A element (m,k) is fed as relu(A[m,k] + ab[k])  (fuses prev layer's bias+relu)
template <int BM, int BN, int BK, int TM, int TN, bool ARELU>
__global__ __launch_bounds__((BM / TM) * (BN / TN)) void gemm_splitk(
    const float* __restrict__ A0, const float* __restrict__ A1,
    const float* __restrict__ B0, const float* __restrict__ B1,
    const float* __restrict__ ab0, const float* __restrict__ ab1,
    float* __restrict__ C0, float* __restrict__ C1,
    int N, int K, int KS, int chunk) {
    constexpr int TX = BM / TM;
    constexpr int TY = BN / TN;
    constexpr int NT = TX * TY;
    constexpr int LA = (BM * BK) / (4 * NT);
    constexpr int LB = (BK * BN) / (4 * NT);
    static_assert(LA >= 1 && LB >= 1, "tile too small for thread count");
    int pair = blockIdx.z / KS;
    int ks = blockIdx.z - pair * KS;
    const float* A = pair ? A1 : A0;
    const float* B = pair ? B1 : B0;
    const float* ab = pair ? ab1 : ab0;
    float* C = pair ? C1 : C0;
    int m0 = blockIdx.x * BM;
    int n0 = blockIdx.y * BN;
    int k0 = ks * chunk;

    __shared__ float As[BK][BM + 4];
    __shared__ float Bs[BK][BN];
    int tid = threadIdx.x;
    int tx = tid % TX;
    int ty = tid / TX;

    int arr[LA], aqr[LA], kbr[LB], bnr[LB];
#pragma unroll
    for (int i = 0; i < LA; i++) {
        int v = tid + i * NT;
        arr[i] = v / (BK / 4);
        aqr[i] = (v % (BK / 4)) * 4;
    }
#pragma unroll
    for (int i = 0; i < LB; i++) {
        int v = tid + i * NT;
        kbr[i] = v / (BN / 4);
        bnr[i] = (v % (BN / 4)) * 4;
    }

    float4 pa[LA], pb[LB];
    auto loadA = [&](int kt) {
#pragma unroll
        for (int i = 0; i < LA; i++) {
            float4 v = *(const float4*)(A + (size_t)(m0 + arr[i]) * K + kt + aqr[i]);
            if (ARELU) {
                float4 b = *(const float4*)(ab + kt + aqr[i]);
                v.x = fmaxf(v.x + b.x, 0.f);
                v.y = fmaxf(v.y + b.y, 0.f);
                v.z = fmaxf(v.z + b.z, 0.f);
                v.w = fmaxf(v.w + b.w, 0.f);
            }
            pa[i] = v;
        }
    };
    auto loadB = [&](int kt) {
#pragma unroll
        for (int i = 0; i < LB; i++)
            pb[i] = *(const float4*)(B + (size_t)(kt + kbr[i]) * N + n0 + bnr[i]);
    };

    float acc[TM][TN] = {};
    loadA(k0);
    loadB(k0);
    for (int kt = k0; kt < k0 + chunk; kt += BK) {
#pragma unroll
        for (int i = 0; i < LA; i++) {
            As[aqr[i] + 0][arr[i]] = pa[i].x;
            As[aqr[i] + 1][arr[i]] = pa[i].y;
            As[aqr[i] + 2][arr[i]] = pa[i].z;
            As[aqr[i] + 3][arr[i]] = pa[i].w;
        }
#pragma unroll
        for (int i = 0; i < LB; i++) *(float4*)&Bs[kbr[i]][bnr[i]] = pb[i];
        __syncthreads();
        if (kt + BK < k0 + chunk) {
            loadA(kt + BK);
            loadB(kt + BK);
        }
#pragma unroll
        for (int k = 0; k < BK; k++) {
            float a[TM], b[TN];
#pragma unroll
            for (int i = 0; i < TM; i++) a[i] = As[k][tx * TM + i];
#pragma unroll
            for (int j = 0; j < TN; j++) b[j] = Bs[k][ty * TN + j];
#pragma unroll
            for (int i = 0; i < TM; i++)
#pragma unroll
                for (int j = 0; j < TN; j++) acc[i][j] += a[i] * b[j];
        }
        __syncthreads();
    }
#pragma unroll
    for (int i = 0; i < TM; i++) {
        float* cp = C + (size_t)(m0 + tx * TM + i) * N + n0 + ty * TN;
#pragma unroll
        for (int j = 0; j < TN; j++) atomicAdd(cp + j, acc[i][j]);
    }
}

// ---------------- heads: apply relu(h+b2) then tiny matvec; argmax routing / g ----------------
__global__ void heads3(const float* __restrict__ h, const float* __restrict__ b2,
                       const float* __restrict__ W3, const float* __restrict__ b3,
                       float* __restrict__ r) {
    int n = blockIdx.x;
    int lane = threadIdx.x;
    const float* hr = h + (size_t)n * 512;
    float p0 = 0.f, p1 = 0.f, p2 = 0.f;
    for (int k = lane; k < 512; k += 64) {
        float hv = fmaxf(hr[k] + b2[k], 0.f);
        p0 += hv * W3[k * 3 + 0];
        p1 += hv * W3[k * 3 + 1];
        p2 += hv * W3[k * 3 + 2];
    }
    for (int off = 32; off; off >>= 1) {
        p0 += __shfl_down(p0, off);
        p1 += __shfl_down(p1, off);
        p2 += __shfl_down(p2, off);
    }
    if (lane == 0) {
        float l0 = p0 + b3[0], l1 = p1 + b3[1], l2 = p2 + b3[2];
        int am = 0;
        float mv = l0;
        if (l1 > mv) { mv = l1; am = 1; }
        if (l2 > mv) { mv = l2; am = 2; }
        float lo = (1.0f - TAU) * 0.5f;
        r[n * 4 + 0] = (am == 0) ? TAU : lo;
        r[n * 4 + 1] = (am == 1) ? TAU : lo;
        r[n * 4 + 2] = (am == 2) ? TAU : lo;
    }
}

__global__ void heads2(const float* __restrict__ h, const float* __restrict__ b2,
                       const float* __restrict__ W3, const float* __restrict__ b3,
                       float* __restrict__ g) {
    int n = blockIdx.x;
    int lane = threadIdx.x;
    const float* hr = h + (size_t)n * 512;
    float p0 = 0.f, p1 = 0.f;
    for (int k = lane; k < 512; k += 64) {
        float hv = fmaxf(hr[k] + b2[k], 0.f);
        p0 += hv * W3[k * 2 + 0];
        p1 += hv * W3[k * 2 + 1];
    }
    for (int off = 32; off; off >>= 1) {
        p0 += __shfl_down(p0, off);
        p1 += __shfl_down(p1, off);
    }
    if (lane == 0) {
        g[n * 2 + 0] = p0 + b3[0];
        g[n * 2 + 1] = p1 + b3[1];
    }
}

// ---------------- res1 = (x2*(g@C2s) + g@bp1) * (r@Wm1s) + r@bp2 ----------------
__global__ void res1_kernel(const float* __restrict__ x2, const float* __restrict__ g,
                            const float* __restrict__ r, const float* __restrict__ C2s,
                            const float* __restrict__ bp1, const float* __restrict__ Wm1s,
                            const float* __restrict__ bp2, float* __restrict__ res1) {
    int idx = blockIdx.x * blockDim.x + threadIdx.x;
    int n = idx / 192;
    int kq = (idx % 192) * 4;
    float g0 = g[n * 2 + 0], g1 = g[n * 2 + 1];
    float r0 = r[n * 4 + 0], r1 = r[n * 4 + 1], r2 = r[n * 4 + 2];
    float4 xv = *(const float4*)(x2 + (size_t)n * 768 + kq);
    float4 c0 = *(const float4*)(C2s + kq);
    float4 c1 = *(const float4*)(C2s + 768 + kq);
    float4 p0 = *(const float4*)(bp1 + kq);
    float4 p1 = *(const float4*)(bp1 + 768 + kq);
    float4 w0 = *(const float4*)(Wm1s + kq);
    float4 w1 = *(const float4*)(Wm1s + 768 + kq);
    float4 w2 = *(const float4*)(Wm1s + 1536 + kq);
    float4 q0 = *(const float4*)(bp2 + kq);
    float4 q1 = *(const float4*)(bp2 + 768 + kq);
    float4 q2 = *(const float4*)(bp2 + 1536 + kq);
    float4 o;
    o.x = (xv.x * (g0 * c0.x + g1 * c1.x) + g0 * p0.x + g1 * p1.x) * (r0 * w0.x + r1 * w1.x + r2 * w2.x) + r0 * q0.x + r1 * q1.x + r2 * q2.x;
    o.y = (xv.y * (g0 * c0.y + g1 * c1.y) + g0 * p0.y + g1 * p1.y) * (r0 * w0.y + r1 * w1.y + r2 * w2.y) + r0 * q0.y + r1 * q1.y + r2 * q2.y;
    o.z = (xv.z * (g0 * c0.z + g1 * c1.z) + g0 * p0.z + g1 * p1.z) * (r0 * w0.z + r1 * w1.z + r2 * w2.z) + r0 * q0.z + r1 * q1.z + r2 * q2.z;
    o.w = (xv.w * (g0 * c0.w + g1 * c1.w) + g0 * p0.w + g1 * p1.w) * (r0 * w0.w + r1 * w1.w + r2 * w2.w) + r0 * q0.w + r1 * q1.w + r2 * q2.w;
    *(float4*)(res1 + (size_t)n * 768 + kq) = o;
}

// ---------------- GCN gather ----------------
template <int D, int NPB, bool RELU>
__global__ void gcn_gather(const float* __restrict__ h, const int* __restrict__ rowst,
                           const int* __restrict__ adj, const float* __restrict__ dinv,
                           const float* __restrict__ bias, float* __restrict__ out) {
    int n = blockIdx.x * NPB + threadIdx.x / D;
    int k = threadIdx.x % D;
    int r0 = rowst[n], r1 = rowst[n + 1];
    float acc = 0.f;
    for (int i = r0; i < r1; i++) {
        int s = adj[i];
        acc += h[(size_t)s * D + k] * dinv[s];
    }
    float v = dinv[n] * acc + bias[k];
    if (RELU) v = fmaxf(v, 0.f);
    out[(size_t)n * D + k] = v;
}

// ---------------- res2 combine ----------------
__global__ void combine_res2(const float* __restrict__ g1out, const float* __restrict__ wm13o,
                             const float* __restrict__ r, const float* __restrict__ wm12,
                             const float* __restrict__ Wm2s, float* __restrict__ res2) {
    int idx = blockIdx.x * blockDim.x + threadIdx.x;
    int n = idx / 64;
    int kq = (idx % 64) * 4;
    float r0 = r[n * 4 + 0], r1 = r[n * 4 + 1], r2 = r[n * 4 + 2];
    float4 a0 = *(const float4*)(wm12 + kq);
    float4 a1 = *(const float4*)(wm12 + 256 + kq);
    float4 a2 = *(const float4*)(wm12 + 512 + kq);
    float4 w0 = *(const float4*)(Wm2s + kq);
    float4 w1 = *(const float4*)(Wm2s + 256 + kq);
    float4 w2 = *(const float4*)(Wm2s + 512 + kq);
    float4 gv = *(const float4*)(g1out + (size_t)n * 256 + kq);
    float4 mv = *(const float4*)(wm13o + (size_t)n * 256 + kq);
    float4 o;
    o.x = (r0 * w0.x + r1 * w1.x + r2 * w2.x) * ((r0 * a0.x + r1 * a1.x + r2 * a2.x) * fmaxf(gv.x, 0.f) + 2e-4f * mv.x);
    o.y = (r0 * w0.y + r1 * w1.y + r2 * w2.y) * ((r0 * a0.y + r1 * a1.y + r2 * a2.y) * fmaxf(gv.y, 0.f) + 2e-4f * mv.y);
    o.z = (r0 * w0.z + r1 * w1.z + r2 * w2.z) * ((r0 * a0.z + r1 * a1.z + r2 * a2.z) * fmaxf(gv.z, 0.f) + 2e-4f * mv.z);
    o.w = (r0 * w0.w + r1 * w1.w + r2 * w2.w) * ((r0 * a0.w + r1 * a1.w + r2 * a2.w) * fmaxf(gv.w, 0.f) + 2e-4f * mv.w);
    *(float4*)(res2 + (size_t)n * 256 + kq) = o;
}

// ---------------- final: log_softmax(h2 @ fc_W + fc_b) ----------------
__global__ void final_fc(const float* __restrict__ h2, const float* __restrict__ fcW,
                         const float* __restrict__ fcb, float* __restrict__ out) {
    int t = threadIdx.x;
    int n = blockIdx.x * 32 + t / 8;
    int j = t % 8;
    const float* hr = h2 + (size_t)n * 32;
    float acc = fcb[j];
#pragma unroll
    for (int i = 0; i < 32; i++) acc += hr[i] * fcW[i * 8 + j];
    float m = acc;
    for (int off = 4; off; off >>= 1) m = fmaxf(m, __shfl_xor(m, off, 8));
    float e = expf(acc - m);
    float s = e;
    for (int off = 4; off; off >>= 1) s += __shfl_xor(s, off, 8);
    out[(size_t)n * 8 + j] = acc - m - logf(s);
}

extern "C" void kernel_launch(void* const* d_in, const int* in_sizes, int n_in,
                              void* d_out, int out_size, void* d_ws, size_t ws_size,
                              hipStream_t stream) {
    const float* x1     = (const float*)d_in[0];
    const float* x11    = (const float*)d_in[1];
    const float* x2     = (const float*)d_in[2];
    const float* mlp_W1 = (const float*)d_in[3];
    const float* mlp_b1 = (const float*)d_in[4];
    const float* mlp_W2 = (const float*)d_in[5];
    const float* mlp_b2 = (const float*)d_in[6];
    const float* mlp_W3 = (const float*)d_in[7];
    const float* mlp_b3 = (const float*)d_in[8];
    const float* m1_W1  = (const float*)d_in[9];
    const float* m1_b1  = (const float*)d_in[10];
    const float* m1_W2  = (const float*)d_in[11];
    const float* m1_b2  = (const float*)d_in[12];
    const float* m1_W3  = (const float*)d_in[13];
    const float* m1_b3  = (const float*)d_in[14];
    const float* wm1    = (const float*)d_in[15];
    const float* bp1    = (const float*)d_in[16];
    const float* bp2    = (const float*)d_in[17];
    const float* wm12   = (const float*)d_in[18];
    const float* wm13   = (const float*)d_in[19];
    const float* class2 = (const float*)d_in[20];
    const float* gcn1_W = (const float*)d_in[21];
    const float* gcn1_b = (const float*)d_in[22];
    const float* wm2    = (const float*)d_in[23];
    const float* gcn2_W = (const float*)d_in[24];
    const float* gcn2_b = (const float*)d_in[25];
    const float* fc_W   = (const float*)d_in[26];
    const float* fc_b   = (const float*)d_in[27];
    const int* eidx     = (const int*)d_in[28];
    const int* esrc = eidx;
    const int* edst = eidx + NE;

    char* ws = (char*)d_ws;
    bool big = ws_size >= (10u << 20);

    // tail scratch (both layouts): placed after the activation region
    size_t tail_off = big ? (8u << 20) : (7u << 20);
    float* rbuf   = (float*)(ws + tail_off);
    float* gbuf   = rbuf + 4096;
    float* C2s    = gbuf + 2048;
    float* Wm1s   = C2s + 1536;
    float* Wm2s   = Wm1s + 2304;
    float* dinv   = Wm2s + 768;
    int*   deg    = (int*)(dinv + 1024);
    int*   rowst  = deg + 1024;
    int*   cursor = rowst + 1040;
    int*   adj    = cursor + 1024;

    hipMemsetAsync(deg, 0, NN * sizeof(int), stream);
    precompute_tabs<<<18, 256, 0, stream>>>(class2, wm1, wm2, C2s, Wm1s, Wm2s);
    count_deg<<<NE / 256, 256, 0, stream>>>(edst, deg);
    scan_deg<<<1, NN, 0, stream>>>(deg, rowst, cursor, dinv);
    fill_adj<<<NE / 256, 256, 0, stream>>>(esrc, edst, cursor, adj);

    if (big) {
        float* hs1a  = (float*)(ws + 0);
        float* hs1b  = (float*)(ws + (2u << 20));
        float* hs2a  = (float*)(ws + (4u << 20));
        float* hs2b  = (float*)(ws + (6u << 20));
        float* res1  = (float*)(ws + 0);            // after heads (hs1 dead)
        float* res2  = (float*)(ws + (3u << 20));
        float* gcnh  = (float*)(ws + (4u << 20));   // after heads (hs2 dead)
        float* wm13o = (float*)(ws + (5u << 20));
        float* g1out = (float*)(ws + (6u << 20));
        float* g2h   = (float*)(ws + (4u << 20));   // after gather1 (gcnh dead)
        float* g2out = (float*)(ws + (5u << 20));   // after combine (wm13o dead)

        hipMemsetAsync(ws, 0, 8u << 20, stream);    // zero hs1a/hs1b/hs2a/hs2b
        // layer1 pair: [x1,x11] @ [mlp_W1,m1_W1] -> hs1a/hs1b   (K=768, KS=4, chunk=192)
        gemm_splitk<64, 64, 16, 4, 4, false><<<dim3(16, 8, 8), 256, 0, stream>>>(
            x1, x11, mlp_W1, m1_W1, nullptr, nullptr, hs1a, hs1b, 512, 768, 4, 192);
        // layer2 pair: relu(hs1+b1) @ W2 -> hs2a/hs2b           (K=512, KS=4, chunk=128)
        gemm_splitk<64, 64, 16, 4, 4, true><<<dim3(16, 8, 8), 256, 0, stream>>>(
            hs1a, hs1b, mlp_W2, m1_W2, mlp_b1, m1_b1, hs2a, hs2b, 512, 512, 4, 128);
        heads3<<<NN, 64, 0, stream>>>(hs2a, mlp_b2, mlp_W3, mlp_b3, rbuf);
        heads2<<<NN, 64, 0, stream>>>(hs2b, m1_b2, m1_W3, m1_b3, gbuf);

        res1_kernel<<<768, 256, 0, stream>>>(x2, gbuf, rbuf, C2s, bp1, Wm1s, bp2, res1);

        hipMemsetAsync(gcnh, 0, 2u << 20, stream);  // gcnh + wm13o
        gemm_splitk<64, 64, 16, 4, 4, false><<<dim3(16, 4, 8), 256, 0, stream>>>(
            res1, res1, gcn1_W, wm13, nullptr, nullptr, gcnh, wm13o, 256, 768, 4, 192);
        gcn_gather<256, 1, false><<<NN, 256, 0, stream>>>(gcnh, rowst, adj, dinv, gcn1_b, g1out);
        combine_res2<<<256, 256, 0, stream>>>(g1out, wm13o, rbuf, wm12, Wm2s, res2);

        hipMemsetAsync(g2h, 0, NN * 32 * sizeof(float), stream);
        gemm_splitk<64, 32, 16, 4, 4, false><<<dim3(16, 1, 4), 128, 0, stream>>>(
            res2, res2, gcn2_W, gcn2_W, nullptr, nullptr, g2h, g2h, 32, 256, 4, 64);
        gcn_gather<32, 2, true><<<NN / 2, 64, 0, stream>>>(g2h, rowst, adj, dinv, gcn2_b, g2out);

        final_fc<<<32, 256, 0, stream>>>(g2out, fc_W, fc_b, (float*)d_out);
    } else {
        // sequential low-memory fallback (7.3 MB, known-good envelope)
        float* hs1   = (float*)(ws + 0);
        float* hs2   = (float*)(ws + (2u << 20));
        float* res1  = (float*)(ws + (4u << 20));
        float* gcnh  = (float*)(ws + 0);
        float* wm13o = (float*)(ws + (1u << 20));
        float* g1out = (float*)(ws + (2u << 20));
        float* res2  = (float*)(ws + (3u << 20));
        float* g2h   = (float*)(ws + 0);
        float* g2out = (float*)(ws + (1u << 20));

        hipMemsetAsync(hs1, 0, 2u << 20, stream);
        gemm_splitk<64, 64, 16, 4, 4, false><<<dim3(16, 8, 4), 256, 0, stream>>>(
            x1, x1, mlp_W1, mlp_W1, nullptr, nullptr, hs1, hs1, 512, 768, 4, 192);
        hipMemsetAsync(hs2, 0, 2u << 20, stream);
        gemm_splitk<64, 64, 16, 4, 4, true><<<dim3(16, 8, 4), 256, 0, stream>>>(
            hs1, hs1, mlp_W2, mlp_W2, mlp_b1, mlp_b1, hs2, hs2, 512, 512, 4, 128);
        heads3<<<NN, 64, 0, stream>>>(hs2, mlp_b2, mlp_W3, mlp_b3, rbuf);

        hipMemsetAsync(hs1, 0, 2u << 20, stream);
        gemm_splitk<64, 64, 16, 4, 4, false><<<dim3(16, 8, 4), 256, 0, stream>>>(
            x11, x11, m1_W1, m1_W1, nullptr, nullptr, hs1, hs1, 512, 768, 4, 192);
        hipMemsetAsync(hs2, 0, 2u << 20, stream);
        gemm_splitk<64, 64, 16, 4, 4, true><<<dim3(16, 8, 4), 256, 0, stream>>>(
            hs1, hs1, m1_W2, m1_W2, m1_b1, m1_b1, hs2, hs2, 512, 512, 4, 128);
        heads2<<<NN, 64, 0, stream>>>(hs2, m1_b2, m1_W3, m1_b3, gbuf);

        res1_kernel<<<768, 256, 0, stream>>>(x2, gbuf, rbuf, C2s, bp1, Wm1s, bp2, res1);

        hipMemsetAsync(gcnh, 0, 2u << 20, stream);  // gcnh + wm13o contiguous
        gemm_splitk<64, 64, 16, 4, 4, false><<<dim3(16, 4, 8), 256, 0, stream>>>(
            res1, res1, gcn1_W, wm13, nullptr, nullptr, gcnh, wm13o, 256, 768, 4, 192);
        gcn_gather<256, 1, false><<<NN, 256, 0, stream>>>(gcnh, rowst, adj, dinv, gcn1_b, g1out);
        combine_res2<<<256, 256, 0, stream>>>(g1out, wm13o, rbuf, wm12, Wm2s, res2);

        hipMemsetAsync(g2h, 0, NN * 32 * sizeof(float), stream);
        gemm_splitk<64, 32, 16, 4, 4, false><<<dim3(16, 1, 4), 128, 0, stream>>>(
            res2, res2, gcn2_W, gcn2_W, nullptr, nullptr, g2h, g2h, 32, 256, 4, 64);
        gcn_gather<32, 2, true><<<NN / 2, 64, 0, stream>>>(g2h, rowst, adj, dinv, gcn2_b, g2out);

        final_fc<<<32, 256, 0, stream>>>(g2out, fc_W, fc_b, (float*)d_out);
    }
}